// Round 7
// baseline (22.592 us; speedup 1.0000x reference)
//
#include <hip/hip_runtime.h>

// GeometryRefiner: 3 Adam iterations on analytic gradient of
// bond + angle + clash + restraint loss. B=2, S=256, A=5.
// 3-dispatch chain (structural minimum: each iteration is a global
// all-to-all dependency; in-kernel grid sync measured ~30us/sync).
//   K1: grad(x0) -> g1, x1
//   K2: grad(x1) -> x2, mv (packed m2,v2)
//   K3: grad(x2) -> out
// Block = 320 threads = 5 waves = 5 atoms (SPLIT=64: one wave per atom).
// 512 blocks = exactly 2 blocks/CU -> uniform 10 waves/CU.
// Stage via global_load_lds; restraint rv + adam state prefetched
// pre-barrier (overlap staging DMA); epilogue spread across lanes 0-2.

#define S_ 256
#define A_ 5
#define NATOM 1280           // S_*A_
#define NB3 3840             // NATOM*3
#define NF4 960              // NB3/4
#define NEL 7680             // B*NB3
#define SPLIT 64
#define BLOCK_ 320           // 5 waves
#define ATOMS_PER_BLOCK 5
#define BLOCKS_PER_BATCH 256 // NATOM/ATOMS_PER_BLOCK
#define GRID_ (2 * BLOCKS_PER_BATCH)

#define COEF_BOND2  (10.0f/1275.0f)
#define COEF_ANGLE2 (10.0f/1536.0f)
#define COEF_CLASH2 (20.0f/1619250.0f)
#define COEF_REST2  (2.0f/32640.0f)
#define TGT_ANG 1.91113553f               // 109.5 * pi / 180

__device__ __forceinline__ void issue_stage(float* xs, const float* xb, int tid) {
    // 960 float4 chunks, 320 threads, 3 iterations. For wave w, iter k:
    // chunk = w*64 + lane + k*320 -> LDS byte offset = chunk*16 =
    // (wave-uniform) + lane*16, satisfying global_load_lds addressing.
    #pragma unroll
    for (int k = 0; k < 3; ++k) {
        int c = tid + k * BLOCK_;
        __builtin_amdgcn_global_load_lds((const __attribute__((address_space(1))) void*)(xb + c * 4),
                                         (__attribute__((address_space(3))) void*)(xs + c * 4),
                                         16, 0, 0);
    }
}

__device__ __forceinline__ void wait_stage() {
    __builtin_amdgcn_s_waitcnt(0x3f70 /* vmcnt(0) */);
    __syncthreads();
}

// Prefetch the 4 restraint values this lane will need (a==0 waves only).
__device__ __forceinline__ void prefetch_rv(const float* rb, int s, int a, int sub,
                                            float* rv) {
    if (a == 0) {
        #pragma unroll
        for (int k = 0; k < S_ / SPLIT; ++k) {
            int j = sub + k * SPLIT;
            int lo = (s < j) ? s : j, hi = (s < j) ? j : s;
            rv[k] = rb[lo * S_ + hi];
        }
    }
}

__device__ __forceinline__ void angle_accum(const float* xs, int q, int role,
                                            float& gx, float& gy, float& gz) {
    const float* P = xs + (q - 1) * 3;
    const float* Q = xs + q * 3;
    const float* R = xs + (q + 1) * 3;
    float v1x = P[0] - Q[0], v1y = P[1] - Q[1], v1z = P[2] - Q[2];
    float v2x = R[0] - Q[0], v2y = R[1] - Q[1], v2z = R[2] - Q[2];
    float n1 = sqrtf(v1x * v1x + v1y * v1y + v1z * v1z);
    float n2 = sqrtf(v2x * v2x + v2y * v2y + v2z * v2z);
    float n1m = fmaxf(n1, 1e-8f), n2m = fmaxf(n2, 1e-8f);
    float dot = v1x * v2x + v1y * v2y + v1z * v2z;
    float inv1 = 1.0f / n1m, inv2 = 1.0f / n2m;
    float inv12 = inv1 * inv2;
    float cosv = dot * inv12;
    float cc = fminf(fmaxf(cosv, -1.0f), 1.0f);
    float ang = acosf(cc);
    float G = 0.0f;
    if (cosv > -1.0f && cosv < 1.0f) {
        G = -COEF_ANGLE2 * (ang - TGT_ANG) * rsqrtf(1.0f - cosv * cosv);
    }
    float a1 = cosv * inv1 * inv1, a2 = cosv * inv2 * inv2;
    float d1x = inv12 * v2x - a1 * v1x;
    float d1y = inv12 * v2y - a1 * v1y;
    float d1z = inv12 * v2z - a1 * v1z;
    float d2x = inv12 * v1x - a2 * v2x;
    float d2y = inv12 * v1y - a2 * v2y;
    float d2z = inv12 * v1z - a2 * v2z;
    if (role == 0)      { gx += G * d1x; gy += G * d1y; gz += G * d1z; }
    else if (role == 2) { gx += G * d2x; gy += G * d2y; gz += G * d2z; }
    else                { gx -= G * (d1x + d2x); gy -= G * (d1y + d2y); gz -= G * (d1z + d2z); }
}

// Full gradient for atom n; after return ALL lanes hold the reduced sum.
__device__ __forceinline__ void grad_body(const float* xs,
                                          int n, int s, int a, int sub,
                                          const float* rv,
                                          float& tx, float& ty, float& tz) {
    const float xn0 = xs[n * 3], xn1 = xs[n * 3 + 1], xn2 = xs[n * 3 + 2];

    // clash partial over residues mr = sub, sub+64, sub+128, sub+192
    float cgx = 0.f, cgy = 0.f, cgz = 0.f;
    #pragma unroll
    for (int k = 0; k < S_ / SPLIT; ++k) {
        int mr = sub + k * SPLIT;
        int dres = mr - s;
        if (dres >= -1 && dres <= 1) continue;
        const float* xm = xs + mr * 15;
        #pragma unroll
        for (int ma = 0; ma < A_; ++ma) {
            float dx = xn0 - xm[ma * 3 + 0];
            float dy = xn1 - xm[ma * 3 + 1];
            float dz = xn2 - xm[ma * 3 + 2];
            float d2 = dx * dx + dy * dy + dz * dz;
            if (d2 > 1e-12f && d2 < 4.0f) {
                float inv = rsqrtf(d2);
                cgx += dx * inv; cgy += dy * inv; cgz += dz * inv;
            }
        }
    }

    // restraint partial (rep atoms only, a == 0; rep index i = s)
    float rgx = 0.f, rgy = 0.f, rgz = 0.f;
    if (a == 0) {
        const int i = s;
        #pragma unroll
        for (int k = 0; k < S_ / SPLIT; ++k) {
            int j = sub + k * SPLIT;
            if (j == i) continue;
            const float* xj = xs + j * 15;
            float dx = xn0 - xj[0], dy = xn1 - xj[1], dz = xn2 - xj[2];
            float d2 = dx * dx + dy * dy + dz * dz;
            if (d2 > 1e-12f) {
                float inv = rsqrtf(d2);
                float dr = d2 * inv;
                float w = (dr - rv[k]) * inv;
                rgx += w * dx; rgy += w * dy; rgz += w * dz;
            }
        }
    }

    tx = -COEF_CLASH2 * cgx + COEF_REST2 * rgx;
    ty = -COEF_CLASH2 * cgy + COEF_REST2 * rgy;
    tz = -COEF_CLASH2 * cgz + COEF_REST2 * rgz;

    // bonds on lanes 0,1 (unified body: neighbor = n-1 / n+1)
    if (sub < 2) {
        bool valid = (sub == 0) ? (n >= 1 && n <= 1275) : (n <= 1274);
        if (valid) {
            int nb = (sub == 0) ? n - 1 : n + 1;
            float dx = xn0 - xs[nb * 3];
            float dy = xn1 - xs[nb * 3 + 1];
            float dz = xn2 - xs[nb * 3 + 2];
            float d2 = dx * dx + dy * dy + dz * dz;
            float inv = rsqrtf(d2);
            float w = COEF_BOND2 * (1.0f - 1.5f * inv);
            tx += w * dx; ty += w * dy; tz += w * dz;
        }
    }
    // angles on lanes 2,3,4 (unified body: q = n+1-role)
    if (sub >= 2 && sub <= 4) {
        int role = sub - 2;
        bool valid = (role == 0) ? (a <= A_ - 3)
                   : (role == 1) ? (a >= 1 && a <= A_ - 2)
                                 : (a >= 2);
        if (valid) angle_accum(xs, n + 1 - role, role, tx, ty, tz);
    }

    #pragma unroll
    for (int m = 1; m < SPLIT; m <<= 1) {
        tx += __shfl_xor(tx, m);
        ty += __shfl_xor(ty, m);
        tz += __shfl_xor(tz, m);
    }
}

// K1: g1 = grad(x0); x1 = adam1(x0, g1)
__global__ __launch_bounds__(BLOCK_) void k1(const float* __restrict__ x0,
                                             const float* __restrict__ restr,
                                             float* __restrict__ g1,
                                             float* __restrict__ x1) {
    __shared__ float xs[NB3];
    const int b = blockIdx.x / BLOCKS_PER_BATCH;
    const int base = (blockIdx.x % BLOCKS_PER_BATCH) * ATOMS_PER_BLOCK;
    const int la = threadIdx.x >> 6;
    const int sub = threadIdx.x & (SPLIT - 1);
    const int n = base + la;
    const int s = n / A_;
    const int a = n - s * A_;

    issue_stage(xs, x0 + b * NB3, threadIdx.x);
    float rv[4];
    prefetch_rv(restr + b * (S_ * S_), s, a, sub, rv);
    wait_stage();

    float tx, ty, tz;
    grad_body(xs, n, s, a, sub, rv, tx, ty, tz);
    if (sub < 3) {
        const int idx = b * NB3 + n * 3 + sub;
        float G = (sub == 0) ? tx : (sub == 1) ? ty : tz;
        g1[idx] = G;
        float mh = (0.1f * G) / 0.1f;
        float vh = (0.001f * G * G) / 0.001f;
        x1[idx] = xs[n * 3 + sub] - 0.01f * mh / (sqrtf(vh) + 1e-8f);
    }
}

// K2: g2 = grad(x1); x2 = adam2 using stored g1; store packed (m2,v2).
__global__ __launch_bounds__(BLOCK_) void k2(const float* __restrict__ x1,
                                             const float* __restrict__ restr,
                                             const float* __restrict__ g1,
                                             float* __restrict__ x2,
                                             float2* __restrict__ mv) {
    __shared__ float xs[NB3];
    const int b = blockIdx.x / BLOCKS_PER_BATCH;
    const int base = (blockIdx.x % BLOCKS_PER_BATCH) * ATOMS_PER_BLOCK;
    const int la = threadIdx.x >> 6;
    const int sub = threadIdx.x & (SPLIT - 1);
    const int n = base + la;
    const int s = n / A_;
    const int a = n - s * A_;
    const int idx = b * NB3 + n * 3 + ((sub < 3) ? sub : 0);

    issue_stage(xs, x1 + b * NB3, threadIdx.x);
    float G1 = g1[idx];                       // prefetch, overlaps staging
    float rv[4];
    prefetch_rv(restr + b * (S_ * S_), s, a, sub, rv);
    wait_stage();

    float tx, ty, tz;
    grad_body(xs, n, s, a, sub, rv, tx, ty, tz);
    if (sub < 3) {
        float G2 = (sub == 0) ? tx : (sub == 1) ? ty : tz;
        float m1 = 0.1f * G1;
        float v1 = 0.001f * G1 * G1;
        float m2 = 0.9f * m1 + 0.1f * G2;
        float v2 = 0.999f * v1 + 0.001f * G2 * G2;
        mv[idx] = make_float2(m2, v2);
        float mh = m2 / 0.19f;
        float vh = v2 / 0.001999f;
        x2[idx] = xs[n * 3 + sub] - 0.01f * mh / (sqrtf(vh) + 1e-8f);
    }
}

// K3: g3 = grad(x2); out = adam3 using stored packed (m2,v2).
__global__ __launch_bounds__(BLOCK_) void k3(const float* __restrict__ x2,
                                             const float* __restrict__ restr,
                                             const float2* __restrict__ mv,
                                             float* __restrict__ out) {
    __shared__ float xs[NB3];
    const int b = blockIdx.x / BLOCKS_PER_BATCH;
    const int base = (blockIdx.x % BLOCKS_PER_BATCH) * ATOMS_PER_BLOCK;
    const int la = threadIdx.x >> 6;
    const int sub = threadIdx.x & (SPLIT - 1);
    const int n = base + la;
    const int s = n / A_;
    const int a = n - s * A_;
    const int idx = b * NB3 + n * 3 + ((sub < 3) ? sub : 0);

    issue_stage(xs, x2 + b * NB3, threadIdx.x);
    float2 MV = mv[idx];                      // prefetch, overlaps staging
    float rv[4];
    prefetch_rv(restr + b * (S_ * S_), s, a, sub, rv);
    wait_stage();

    float tx, ty, tz;
    grad_body(xs, n, s, a, sub, rv, tx, ty, tz);
    if (sub < 3) {
        float G3 = (sub == 0) ? tx : (sub == 1) ? ty : tz;
        float m3 = 0.9f * MV.x + 0.1f * G3;
        float v3 = 0.999f * MV.y + 0.001f * G3 * G3;
        float mh = m3 / 0.271f;
        float vh = v3 / 0.002997001f;
        out[idx] = xs[n * 3 + sub] - 0.01f * mh / (sqrtf(vh) + 1e-8f);
    }
}

extern "C" void kernel_launch(void* const* d_in, const int* in_sizes, int n_in,
                              void* d_out, int out_size, void* d_ws, size_t ws_size,
                              hipStream_t stream) {
    const float* coords = (const float*)d_in[0];
    const float* restr  = (const float*)d_in[1];
    float* out = (float*)d_out;
    float* ws  = (float*)d_ws;
    float*  g1 = ws;                       // NEL
    float*  x1 = ws + NEL;                 // NEL
    float*  x2 = ws + 2 * NEL;             // NEL
    float2* mv = (float2*)(ws + 3 * NEL);  // NEL float2

    k1<<<GRID_, BLOCK_, 0, stream>>>(coords, restr, g1, x1);
    k2<<<GRID_, BLOCK_, 0, stream>>>(x1, restr, g1, x2, mv);
    k3<<<GRID_, BLOCK_, 0, stream>>>(x2, restr, mv, out);
}